// Round 1
// 492.125 us; speedup vs baseline: 1.0480x; 1.0480x over previous
//
#include <hip/hip_runtime.h>

// Problem constants
#define NN    8192          // N
#define DD    384           // dim
#define RR    64            // rank
#define BNROW 131072        // B*N
#define NGRP  2048          // B*g

typedef __attribute__((ext_vector_type(8))) short short8;   // 8 bf16 (A/B frag)
typedef __attribute__((ext_vector_type(4))) float floatx4;  // C/D frag

__device__ __forceinline__ float silu_f(float x) {
    return x / (1.0f + __expf(-x));
}

// RNE round fp32 -> bf16 bits (low 16)
__device__ __forceinline__ unsigned bfr(float x) {
    unsigned u = __float_as_uint(x);
    return (u + 0x7fffu + ((u >> 16) & 1u)) >> 16;
}

// pack two fp32 -> two bf16 (RNE) in one uint
__device__ __forceinline__ unsigned bf2(float a, float b) {
    return bfr(a) | (bfr(b) << 16);
}

union S8 { unsigned u[4]; short8 s; };

// ---------------------------------------------------------------------------
// Kernel P (prep): one-time bf16 conversion of the shared weights into the
// workspace. Wd 64x384, Wu 384x64, Wa 64x64 -- all natural row-major, no pad
// (these live in L2 for the whole run; per-block LDS staging of them was what
// capped kA to 3 blocks/CU and kC to 2 blocks/CU).
// Grid 52x256 = 13312 threads = 6144 + 6144 + 1024 float4s.
// ---------------------------------------------------------------------------
__global__ __launch_bounds__(256) void kP(const float* __restrict__ Wd,
                                          const float* __restrict__ Wu,
                                          const float* __restrict__ Wa,
                                          unsigned short* __restrict__ WdB,
                                          unsigned short* __restrict__ WuB,
                                          unsigned short* __restrict__ WaB) {
    int i = blockIdx.x * 256 + threadIdx.x;
    const float* s;
    unsigned short* d;
    if (i < 6144)        { s = Wd + i * 4;           d = WdB + i * 4; }
    else if (i < 12288)  { s = Wu + (i - 6144) * 4;  d = WuB + (i - 6144) * 4; }
    else                 { s = Wa + (i - 12288) * 4; d = WaB + (i - 12288) * 4; }
    float4 v = *(const float4*)s;
    *(uint2*)d = make_uint2(bf2(v.x, v.y), bf2(v.z, v.w));
}

// ---------------------------------------------------------------------------
// Kernel A (MFMA): h = silu(input @ Wd^T + bd)
// No LDS. B-frags read straight from global WdB (48 KB, L2-resident).
// All 24 A-row float4 loads pre-issued (24 KB in flight per wave) so the
// kernel is HBM-BW-bound instead of latency-bound.
// Block = 64 rows (4 waves x 16), grid 2048.
// ---------------------------------------------------------------------------
__global__ __launch_bounds__(256) void kA(const float* __restrict__ in,
                                          const unsigned short* __restrict__ WdB,
                                          const float* __restrict__ bd,
                                          float* __restrict__ h) {
    const int tid = threadIdx.x;
    const int lane = tid & 63, w = tid >> 6;
    const int quad = lane >> 4, lr = lane & 15;
    const int grow = blockIdx.x * 64 + w * 16 + lr;    // this lane's A-row
    const float* arow = in + grow * DD + quad * 8;

    float4 v0[12], v1[12];
    #pragma unroll
    for (int ks = 0; ks < 12; ++ks) {
        v0[ks] = *(const float4*)(arow + ks * 32);
        v1[ks] = *(const float4*)(arow + ks * 32 + 4);
    }

    floatx4 acc[4] = {};
    #pragma unroll
    for (int ks = 0; ks < 12; ++ks) {
        S8 a;
        a.u[0] = bf2(v0[ks].x, v0[ks].y); a.u[1] = bf2(v0[ks].z, v0[ks].w);
        a.u[2] = bf2(v1[ks].x, v1[ks].y); a.u[3] = bf2(v1[ks].z, v1[ks].w);
        #pragma unroll
        for (int n = 0; n < 4; ++n) {
            const short8 b = *(const short8*)&WdB[(n * 16 + lr) * DD + ks * 32 + quad * 8];
            acc[n] = __builtin_amdgcn_mfma_f32_16x16x32_bf16(a.s, b, acc[n], 0, 0, 0);
        }
    }
    // D layout: row = quad*4 + i, col = n*16 + lr
    const int orow0 = blockIdx.x * 64 + w * 16 + quad * 4;
    #pragma unroll
    for (int n = 0; n < 4; ++n) {
        float bb = bd[n * 16 + lr];
        #pragma unroll
        for (int i = 0; i < 4; ++i)
            h[(orow0 + i) * 64 + n * 16 + lr] = silu_f(acc[n][i] + bb);
    }
}

// ---------------------------------------------------------------------------
// Kernel B (MFMA, split-bf16): per (b,g) group, one block (4 waves):
//   X = gather(h, idx0); f = U^T X; f += silu(LN_r(f) @ Wa^T + ba); y1 = U f
// The two U-matmuls use a hi/lo bf16 split with 3 MFMA products
// (Ah*Bh + Ah*Bl + Al*Bh): error ~2^-16 relative == fp32-class, so numerics
// match the old fp32 MAC path. Adapter matmul is single bf16 (its output is
// a 0.02-scaled correction). LDS traffic drops 384 -> ~50 ds_read_b128 per
// thread vs the fp32 register-tiled version; 36.9 KB LDS -> 4 blocks/CU.
// Buffer reuse over phases:
//   AH: Ut_hi -> LNf (per-wave rows) -> Un_hi        AL: Ut_lo -> Un_lo
//   BH: Xt_hi -> fT_hi                               BL: Xt_lo -> fT_lo
// ---------------------------------------------------------------------------
__global__ __launch_bounds__(256) void kB(const float* __restrict__ h,
                                          const float* __restrict__ U1,
                                          const int*   __restrict__ idx0,
                                          const unsigned short* __restrict__ WaB,
                                          const float* __restrict__ ba,
                                          const float* __restrict__ gamma,
                                          const float* __restrict__ beta,
                                          float* __restrict__ y1) {
    __shared__ unsigned short AH[64 * 72];
    __shared__ unsigned short AL[64 * 72];
    __shared__ unsigned short BH[64 * 72];
    __shared__ unsigned short BL[64 * 72];
    const int tid = threadIdx.x;
    // XCD-chunked swizzle (2048 % 8 == 0 -> bijective): keeps the 128 blocks
    // sharing one batch's 2.1 MB h-slice on the same XCD's L2.
    const int bg = ((blockIdx.x & 7) << 8) | (blockIdx.x >> 3);
    const int b  = bg >> 7;
    const float* U = U1 + bg * 4096;

    // ---- stage: Ut = U^T (hi/lo), Xt = X^T (hi/lo), transposed scatter
    #pragma unroll
    for (int it = 0; it < 4; ++it) {
        int idx = it * 256 + tid;
        int row = idx >> 4;          // t
        int kq  = idx & 15;          // col group
        float4 u = *(const float4*)(U + row * 64 + kq * 4);
        int src = idx0[bg * 64 + row];
        float4 x = *(const float4*)(h + (b * NN + src) * 64 + kq * 4);
        float uv[4] = {u.x, u.y, u.z, u.w};
        float xv[4] = {x.x, x.y, x.z, x.w};
        #pragma unroll
        for (int j = 0; j < 4; ++j) {
            unsigned uh = bfr(uv[j]);
            AH[(4 * kq + j) * 72 + row] = (unsigned short)uh;
            AL[(4 * kq + j) * 72 + row] = (unsigned short)bfr(uv[j] - __uint_as_float(uh << 16));
            unsigned xh = bfr(xv[j]);
            BH[(4 * kq + j) * 72 + row] = (unsigned short)xh;
            BL[(4 * kq + j) * 72 + row] = (unsigned short)bfr(xv[j] - __uint_as_float(xh << 16));
        }
    }
    __syncthreads();

    const int lane = tid & 63, w = tid >> 6;
    const int quad = lane >> 4, lr = lane & 15;
    const int mrow = w * 16 + lr;

    // ---- m1: f[s][r] = sum_t U[t][s] X[t][r]  (split 3-product)
    floatx4 f[4] = {};
    #pragma unroll
    for (int k = 0; k < 2; ++k) {
        const short8 aH = *(const short8*)&AH[mrow * 72 + k * 32 + quad * 8];
        const short8 aL = *(const short8*)&AL[mrow * 72 + k * 32 + quad * 8];
        #pragma unroll
        for (int n = 0; n < 4; ++n) {
            const short8 bh = *(const short8*)&BH[(n * 16 + lr) * 72 + k * 32 + quad * 8];
            const short8 bl = *(const short8*)&BL[(n * 16 + lr) * 72 + k * 32 + quad * 8];
            f[n] = __builtin_amdgcn_mfma_f32_16x16x32_bf16(aH, bh, f[n], 0, 0, 0);
            f[n] = __builtin_amdgcn_mfma_f32_16x16x32_bf16(aH, bl, f[n], 0, 0, 0);
            f[n] = __builtin_amdgcn_mfma_f32_16x16x32_bf16(aL, bh, f[n], 0, 0, 0);
        }
    }

    // ---- LN over r. D layout: row s = 16w + quad*4 + i spread over the 16
    // lanes sharing quad (masks 1..8 stay inside the 16-lane group).
    float gv[4], bv[4];
    #pragma unroll
    for (int n = 0; n < 4; ++n) { gv[n] = gamma[n * 16 + lr]; bv[n] = beta[n * 16 + lr]; }
    #pragma unroll
    for (int i = 0; i < 4; ++i) {
        float sm = f[0][i] + f[1][i] + f[2][i] + f[3][i];
        float sq = f[0][i]*f[0][i] + f[1][i]*f[1][i] + f[2][i]*f[2][i] + f[3][i]*f[3][i];
        #pragma unroll
        for (int mask = 1; mask <= 8; mask <<= 1) {
            sm += __shfl_xor(sm, mask, 64);
            sq += __shfl_xor(sq, mask, 64);
        }
        float mean = sm * 0.015625f;
        float var  = sq * 0.015625f - mean * mean;
        float rstd = rsqrtf(var + 1e-5f);
        int srow = w * 16 + quad * 4 + i;
        // LNf -> AH rows [16w,16w+16): wave-private rows, no barrier needed
        // (other waves only touch their own AH rows in m1/m2).
        #pragma unroll
        for (int n = 0; n < 4; ++n) {
            float ln = (f[n][i] - mean) * rstd * gv[n] + bv[n];
            AH[srow * 72 + n * 16 + lr] = (unsigned short)bfr(ln);
        }
    }

    // ---- m2: a[s][j] = sum_r LNf[s][r] Wa[j][r]; B straight from global
    // (WaB is 8 KB, L1/L2-resident, shared by all 2048 blocks).
    floatx4 av[4] = {};
    #pragma unroll
    for (int k = 0; k < 2; ++k) {
        const short8 a2 = *(const short8*)&AH[mrow * 72 + k * 32 + quad * 8];
        #pragma unroll
        for (int n = 0; n < 4; ++n) {
            const short8 bw = *(const short8*)&WaB[(n * 16 + lr) * 64 + k * 32 + quad * 8];
            av[n] = __builtin_amdgcn_mfma_f32_16x16x32_bf16(a2, bw, av[n], 0, 0, 0);
        }
    }
    float bav[4];
    #pragma unroll
    for (int n = 0; n < 4; ++n) bav[n] = ba[n * 16 + lr];
    #pragma unroll
    for (int n = 0; n < 4; ++n)
        #pragma unroll
        for (int i = 0; i < 4; ++i)
            f[n][i] += silu_f(av[n][i] + bav[n]);

    __syncthreads();   // all waves done reading Xt (BH/BL) in m1

    // ---- write fT (hi/lo) into BH/BL; restage Un = U natural (hi/lo) into
    // the wave-private rows of AH/AL (U re-read hits L2).
    #pragma unroll
    for (int n = 0; n < 4; ++n)
        #pragma unroll
        for (int i = 0; i < 4; ++i) {
            float v = f[n][i];
            unsigned hb = bfr(v);
            BH[(n * 16 + lr) * 72 + w * 16 + quad * 4 + i] = (unsigned short)hb;
            BL[(n * 16 + lr) * 72 + w * 16 + quad * 4 + i] =
                (unsigned short)bfr(v - __uint_as_float(hb << 16));
        }
    #pragma unroll
    for (int c = 0; c < 4; ++c) {
        float4 u = *(const float4*)(U + mrow * 64 + quad * 16 + c * 4);
        float uv[4] = {u.x, u.y, u.z, u.w};
        unsigned hh[4], ll[4];
        #pragma unroll
        for (int j = 0; j < 4; ++j) {
            hh[j] = bfr(uv[j]);
            ll[j] = bfr(uv[j] - __uint_as_float(hh[j] << 16));
        }
        *(uint2*)&AH[mrow * 72 + quad * 16 + c * 4] =
            make_uint2(hh[0] | (hh[1] << 16), hh[2] | (hh[3] << 16));
        *(uint2*)&AL[mrow * 72 + quad * 16 + c * 4] =
            make_uint2(ll[0] | (ll[1] << 16), ll[2] | (ll[3] << 16));
    }
    __syncthreads();   // fT complete across waves

    // ---- m3: y[p][r] = sum_s U[p][s] f[s][r]  (split 3-product)
    floatx4 y[4] = {};
    #pragma unroll
    for (int k = 0; k < 2; ++k) {
        const short8 aH = *(const short8*)&AH[mrow * 72 + k * 32 + quad * 8];
        const short8 aL = *(const short8*)&AL[mrow * 72 + k * 32 + quad * 8];
        #pragma unroll
        for (int n = 0; n < 4; ++n) {
            const short8 bh = *(const short8*)&BH[(n * 16 + lr) * 72 + k * 32 + quad * 8];
            const short8 bl = *(const short8*)&BL[(n * 16 + lr) * 72 + k * 32 + quad * 8];
            y[n] = __builtin_amdgcn_mfma_f32_16x16x32_bf16(aH, bh, y[n], 0, 0, 0);
            y[n] = __builtin_amdgcn_mfma_f32_16x16x32_bf16(aH, bl, y[n], 0, 0, 0);
            y[n] = __builtin_amdgcn_mfma_f32_16x16x32_bf16(aL, bh, y[n], 0, 0, 0);
        }
    }
    const int orow = bg * 64 + w * 16 + quad * 4;
    #pragma unroll
    for (int n = 0; n < 4; ++n)
        #pragma unroll
        for (int i = 0; i < 4; ++i)
            y1[(orow + i) * 64 + n * 16 + lr] = y[n][i];
}

// ---------------------------------------------------------------------------
// Kernel C (MFMA): out = (gather(y1, idx1) + y1 + h) @ Wu^T + bu
// Wu b-frags straight from global WuB (48 KB, L2-resident). Only the X tile
// (9 KB) lives in LDS -> 8 blocks/CU (was 2 with the 55 KB Wu stage).
// ---------------------------------------------------------------------------
__global__ __launch_bounds__(256) void kC(const float* __restrict__ h,
                                          const float* __restrict__ y1,
                                          const int*   __restrict__ idx1,
                                          const unsigned short* __restrict__ WuB,
                                          const float* __restrict__ bu,
                                          float* __restrict__ out) {
    __shared__ unsigned short Xs[64 * 72];    // [m][k], stride 72 (36w ≡ 4 mod 32)
    const int tid = threadIdx.x;
    const int bid = ((blockIdx.x & 7) << 8) | (blockIdx.x >> 3);  // XCD swizzle
    const int m0 = bid * 64;
    const int b  = m0 >> 13;
    const int n0 = m0 & (NN - 1);

    // stage X = gather(y1) + y1 + h, convert to bf16
    #pragma unroll
    for (int it = 0; it < 4; ++it) {
        int idx = it * 256 + tid;
        int r = idx >> 4, kq = idx & 15;
        int i1 = idx1[b * NN + n0 + r];
        const float4 ya = *(const float4*)(y1 + (b * NN + i1) * 64 + kq * 4);
        const float4 yb = *(const float4*)(y1 + (m0 + r) * 64 + kq * 4);
        const float4 hh = *(const float4*)(h  + (m0 + r) * 64 + kq * 4);
        *(uint2*)&Xs[r * 72 + kq * 4] =
            make_uint2(bf2(ya.x + yb.x + hh.x, ya.y + yb.y + hh.y),
                       bf2(ya.z + yb.z + hh.z, ya.w + yb.w + hh.w));
    }
    __syncthreads();

    const int lane = tid & 63, w = tid >> 6;
    const int quad = lane >> 4, lr = lane & 15;
    const short8 a0 = *(const short8*)&Xs[(w * 16 + lr) * 72 + quad * 8];
    const short8 a1 = *(const short8*)&Xs[(w * 16 + lr) * 72 + 32 + quad * 8];
    const int orow0 = m0 + w * 16 + quad * 4;

    #pragma unroll
    for (int nt = 0; nt < 24; ++nt) {
        const short8 b0 = *(const short8*)&WuB[(nt * 16 + lr) * 64 + quad * 8];
        const short8 b1 = *(const short8*)&WuB[(nt * 16 + lr) * 64 + 32 + quad * 8];
        floatx4 d = {};
        d = __builtin_amdgcn_mfma_f32_16x16x32_bf16(a0, b0, d, 0, 0, 0);
        d = __builtin_amdgcn_mfma_f32_16x16x32_bf16(a1, b1, d, 0, 0, 0);
        const float bb = bu[nt * 16 + lr];
        #pragma unroll
        for (int i = 0; i < 4; ++i)
            out[(orow0 + i) * DD + nt * 16 + lr] = d[i] + bb;
    }
}

// ---------------------------------------------------------------------------
extern "C" void kernel_launch(void* const* d_in, const int* in_sizes, int n_in,
                              void* d_out, int out_size, void* d_ws, size_t ws_size,
                              hipStream_t stream) {
    const float* input = (const float*)d_in[0];
    const float* subU  = (const float*)d_in[1];
    const int*   idx   = (const int*)  d_in[2];
    const float* Wd    = (const float*)d_in[3];
    const float* bd    = (const float*)d_in[4];
    const float* Wu    = (const float*)d_in[5];
    const float* bu    = (const float*)d_in[6];
    const float* Wa    = (const float*)d_in[7];
    const float* ba    = (const float*)d_in[8];
    const float* gamma = (const float*)d_in[9];
    const float* beta  = (const float*)d_in[10];
    float* out = (float*)d_out;

    float* h  = (float*)d_ws;                             // [BN, 64] f32
    float* y1 = h + 8388608;                              // [BN, 64] f32
    unsigned short* WdB = (unsigned short*)(y1 + 8388608); // 64*384 bf16
    unsigned short* WuB = WdB + 24576;                     // 384*64 bf16
    unsigned short* WaB = WuB + 24576;                     // 64*64  bf16

    const float* U1   = subU + 8388608; // sub_U[1] (branch 0 is dead code)
    const int*   idx0 = idx;
    const int*   idx1 = idx + BNROW;

    kP<<<52,   256, 0, stream>>>(Wd, Wu, Wa, WdB, WuB, WaB);
    kA<<<2048, 256, 0, stream>>>(input, WdB, bd, h);
    kB<<<2048, 256, 0, stream>>>(h, U1, idx0, WaB, ba, gamma, beta, y1);
    kC<<<2048, 256, 0, stream>>>(h, y1, idx1, WuB, bu, out);
}

// Round 2
// 470.169 us; speedup vs baseline: 1.0969x; 1.0467x over previous
//
#include <hip/hip_runtime.h>

// Problem constants
#define NN    8192          // N
#define DD    384           // dim
#define RR    64            // rank
#define BNROW 131072        // B*N
#define NGRP  2048          // B*g

typedef __attribute__((ext_vector_type(8))) short short8;            // 8 bf16 (A/B frag)
typedef __attribute__((ext_vector_type(4))) float floatx4;           // C/D frag
typedef __attribute__((ext_vector_type(4))) unsigned short ushortx4; // 4 bf16 (8B load)

__device__ __forceinline__ float silu_f(float x) {
    return x / (1.0f + __expf(-x));
}

// RNE round fp32 -> bf16 bits (low 16)
__device__ __forceinline__ unsigned bfr(float x) {
    unsigned u = __float_as_uint(x);
    return (u + 0x7fffu + ((u >> 16) & 1u)) >> 16;
}

// pack two fp32 -> two bf16 (RNE) in one uint
__device__ __forceinline__ unsigned bf2(float a, float b) {
    return bfr(a) | (bfr(b) << 16);
}

// bf16 bits -> fp32
__device__ __forceinline__ float b2f(unsigned short v) {
    return __uint_as_float(((unsigned)v) << 16);
}

union S8 { unsigned u[4]; short8 s; };

// ---------------------------------------------------------------------------
// Kernel P (prep): one-time bf16 conversion of the shared weights into the
// workspace (Wd 64x384, Wu 384x64, Wa 64x64; all L2-resident for the run).
// ---------------------------------------------------------------------------
__global__ __launch_bounds__(256) void kP(const float* __restrict__ Wd,
                                          const float* __restrict__ Wu,
                                          const float* __restrict__ Wa,
                                          unsigned short* __restrict__ WdB,
                                          unsigned short* __restrict__ WuB,
                                          unsigned short* __restrict__ WaB) {
    int i = blockIdx.x * 256 + threadIdx.x;
    const float* s;
    unsigned short* d;
    if (i < 6144)        { s = Wd + i * 4;           d = WdB + i * 4; }
    else if (i < 12288)  { s = Wu + (i - 6144) * 4;  d = WuB + (i - 6144) * 4; }
    else                 { s = Wa + (i - 12288) * 4; d = WaB + (i - 12288) * 4; }
    float4 v = *(const float4*)s;
    *(uint2*)d = make_uint2(bf2(v.x, v.y), bf2(v.z, v.w));
}

// ---------------------------------------------------------------------------
// Kernel A (MFMA): h = silu(input @ Wd^T + bd), h stored BF16 (halves h
// write traffic; h's 2^-9 rel quantization is absorbed by kC's X-split).
// No LDS; B-frags straight from L2-resident WdB. Block = 64 rows, grid 2048.
// ---------------------------------------------------------------------------
__global__ __launch_bounds__(256) void kA(const float* __restrict__ in,
                                          const unsigned short* __restrict__ WdB,
                                          const float* __restrict__ bd,
                                          unsigned short* __restrict__ h) {
    const int tid = threadIdx.x;
    const int lane = tid & 63, w = tid >> 6;
    const int quad = lane >> 4, lr = lane & 15;
    const int grow = blockIdx.x * 64 + w * 16 + lr;    // this lane's A-row
    const float* arow = in + grow * DD + quad * 8;

    float4 v0[12], v1[12];
    #pragma unroll
    for (int ks = 0; ks < 12; ++ks) {
        v0[ks] = *(const float4*)(arow + ks * 32);
        v1[ks] = *(const float4*)(arow + ks * 32 + 4);
    }

    floatx4 acc[4] = {};
    #pragma unroll
    for (int ks = 0; ks < 12; ++ks) {
        S8 a;
        a.u[0] = bf2(v0[ks].x, v0[ks].y); a.u[1] = bf2(v0[ks].z, v0[ks].w);
        a.u[2] = bf2(v1[ks].x, v1[ks].y); a.u[3] = bf2(v1[ks].z, v1[ks].w);
        #pragma unroll
        for (int n = 0; n < 4; ++n) {
            const short8 b = *(const short8*)&WdB[(n * 16 + lr) * DD + ks * 32 + quad * 8];
            acc[n] = __builtin_amdgcn_mfma_f32_16x16x32_bf16(a.s, b, acc[n], 0, 0, 0);
        }
    }
    // D layout: row = quad*4 + i, col = n*16 + lr
    const int orow0 = blockIdx.x * 64 + w * 16 + quad * 4;
    #pragma unroll
    for (int n = 0; n < 4; ++n) {
        float bb = bd[n * 16 + lr];
        #pragma unroll
        for (int i = 0; i < 4; ++i)
            h[(orow0 + i) * 64 + n * 16 + lr] =
                (unsigned short)bfr(silu_f(acc[n][i] + bb));
    }
}

// ---------------------------------------------------------------------------
// Kernel B (MFMA, split-bf16): per (b,g) group, one block (4 waves):
//   X = gather(h, idx0); f = U^T X; f += silu(LN_r(f) @ Wa^T + ba); y1 = U f
// X is now bf16 from storage -> m1 needs only U hi/lo (2-product, 16 MFMA).
// m3 (y = U f) keeps the full 3-product split (f is fp32 in-kernel).
// y1 stored BF16. Buffers (stride 72, 36.9 KB total, 4 blocks/CU):
//   AH: Ut_hi -> LNf (wave-private rows) -> Un_hi     AL: Ut_lo -> Un_lo
//   BH: Xt (bf16) -> fT_hi                            BL: (unused) -> fT_lo
// ---------------------------------------------------------------------------
__global__ __launch_bounds__(256) void kB(const unsigned short* __restrict__ h,
                                          const float* __restrict__ U1,
                                          const int*   __restrict__ idx0,
                                          const unsigned short* __restrict__ WaB,
                                          const float* __restrict__ ba,
                                          const float* __restrict__ gamma,
                                          const float* __restrict__ beta,
                                          unsigned short* __restrict__ y1) {
    __shared__ unsigned short AH[64 * 72];
    __shared__ unsigned short AL[64 * 72];
    __shared__ unsigned short BH[64 * 72];
    __shared__ unsigned short BL[64 * 72];
    const int tid = threadIdx.x;
    // XCD-chunked swizzle (2048 % 8 == 0 -> bijective)
    const int bg = ((blockIdx.x & 7) << 8) | (blockIdx.x >> 3);
    const int b  = bg >> 7;
    const float* U = U1 + bg * 4096;

    // ---- stage: Ut = U^T (hi/lo), Xt = X^T (bf16 pass-through), transposed
    #pragma unroll
    for (int it = 0; it < 4; ++it) {
        int idx = it * 256 + tid;
        int row = idx >> 4;          // t
        int kq  = idx & 15;          // col group
        float4 u = *(const float4*)(U + row * 64 + kq * 4);
        int src = idx0[bg * 64 + row];
        ushortx4 x = *(const ushortx4*)&h[(b * NN + src) * 64 + kq * 4];
        float uv[4] = {u.x, u.y, u.z, u.w};
        #pragma unroll
        for (int j = 0; j < 4; ++j) {
            unsigned uh = bfr(uv[j]);
            AH[(4 * kq + j) * 72 + row] = (unsigned short)uh;
            AL[(4 * kq + j) * 72 + row] = (unsigned short)bfr(uv[j] - __uint_as_float(uh << 16));
            BH[(4 * kq + j) * 72 + row] = x[j];
        }
    }
    __syncthreads();

    const int lane = tid & 63, w = tid >> 6;
    const int quad = lane >> 4, lr = lane & 15;
    const int mrow = w * 16 + lr;

    // ---- m1: f[s][r] = sum_t U[t][s] X[t][r]  (U split 2-product, X bf16)
    floatx4 f[4] = {};
    #pragma unroll
    for (int k = 0; k < 2; ++k) {
        const short8 aH = *(const short8*)&AH[mrow * 72 + k * 32 + quad * 8];
        const short8 aL = *(const short8*)&AL[mrow * 72 + k * 32 + quad * 8];
        #pragma unroll
        for (int n = 0; n < 4; ++n) {
            const short8 bh = *(const short8*)&BH[(n * 16 + lr) * 72 + k * 32 + quad * 8];
            f[n] = __builtin_amdgcn_mfma_f32_16x16x32_bf16(aH, bh, f[n], 0, 0, 0);
            f[n] = __builtin_amdgcn_mfma_f32_16x16x32_bf16(aL, bh, f[n], 0, 0, 0);
        }
    }

    // ---- LN over r. D layout: row s = 16w + quad*4 + i; masks 1..8 stay
    // inside the 16-lane group.
    float gv[4], bv[4];
    #pragma unroll
    for (int n = 0; n < 4; ++n) { gv[n] = gamma[n * 16 + lr]; bv[n] = beta[n * 16 + lr]; }
    #pragma unroll
    for (int i = 0; i < 4; ++i) {
        float sm = f[0][i] + f[1][i] + f[2][i] + f[3][i];
        float sq = f[0][i]*f[0][i] + f[1][i]*f[1][i] + f[2][i]*f[2][i] + f[3][i]*f[3][i];
        #pragma unroll
        for (int mask = 1; mask <= 8; mask <<= 1) {
            sm += __shfl_xor(sm, mask, 64);
            sq += __shfl_xor(sq, mask, 64);
        }
        float mean = sm * 0.015625f;
        float var  = sq * 0.015625f - mean * mean;
        float rstd = rsqrtf(var + 1e-5f);
        int srow = w * 16 + quad * 4 + i;
        // LNf -> AH rows [16w,16w+16): wave-private, no barrier needed.
        #pragma unroll
        for (int n = 0; n < 4; ++n) {
            float ln = (f[n][i] - mean) * rstd * gv[n] + bv[n];
            AH[srow * 72 + n * 16 + lr] = (unsigned short)bfr(ln);
        }
    }

    // ---- m2: a[s][j] = sum_r LNf[s][r] Wa[j][r]; B straight from global
    floatx4 av[4] = {};
    #pragma unroll
    for (int k = 0; k < 2; ++k) {
        const short8 a2 = *(const short8*)&AH[mrow * 72 + k * 32 + quad * 8];
        #pragma unroll
        for (int n = 0; n < 4; ++n) {
            const short8 bw = *(const short8*)&WaB[(n * 16 + lr) * 64 + k * 32 + quad * 8];
            av[n] = __builtin_amdgcn_mfma_f32_16x16x32_bf16(a2, bw, av[n], 0, 0, 0);
        }
    }
    float bav[4];
    #pragma unroll
    for (int n = 0; n < 4; ++n) bav[n] = ba[n * 16 + lr];
    #pragma unroll
    for (int n = 0; n < 4; ++n)
        #pragma unroll
        for (int i = 0; i < 4; ++i)
            f[n][i] += silu_f(av[n][i] + bav[n]);

    __syncthreads();   // all waves done reading Xt (BH) in m1

    // ---- write fT (hi/lo) into BH/BL; restage Un = U natural (hi/lo) into
    // the wave-private rows of AH/AL (U re-read hits L2).
    #pragma unroll
    for (int n = 0; n < 4; ++n)
        #pragma unroll
        for (int i = 0; i < 4; ++i) {
            float v = f[n][i];
            unsigned hb = bfr(v);
            BH[(n * 16 + lr) * 72 + w * 16 + quad * 4 + i] = (unsigned short)hb;
            BL[(n * 16 + lr) * 72 + w * 16 + quad * 4 + i] =
                (unsigned short)bfr(v - __uint_as_float(hb << 16));
        }
    #pragma unroll
    for (int c = 0; c < 4; ++c) {
        float4 u = *(const float4*)(U + mrow * 64 + quad * 16 + c * 4);
        float uv[4] = {u.x, u.y, u.z, u.w};
        unsigned hh[4], ll[4];
        #pragma unroll
        for (int j = 0; j < 4; ++j) {
            hh[j] = bfr(uv[j]);
            ll[j] = bfr(uv[j] - __uint_as_float(hh[j] << 16));
        }
        *(uint2*)&AH[mrow * 72 + quad * 16 + c * 4] =
            make_uint2(hh[0] | (hh[1] << 16), hh[2] | (hh[3] << 16));
        *(uint2*)&AL[mrow * 72 + quad * 16 + c * 4] =
            make_uint2(ll[0] | (ll[1] << 16), ll[2] | (ll[3] << 16));
    }
    __syncthreads();   // fT complete across waves

    // ---- m3: y[p][r] = sum_s U[p][s] f[s][r]  (split 3-product)
    floatx4 y[4] = {};
    #pragma unroll
    for (int k = 0; k < 2; ++k) {
        const short8 aH = *(const short8*)&AH[mrow * 72 + k * 32 + quad * 8];
        const short8 aL = *(const short8*)&AL[mrow * 72 + k * 32 + quad * 8];
        #pragma unroll
        for (int n = 0; n < 4; ++n) {
            const short8 bh = *(const short8*)&BH[(n * 16 + lr) * 72 + k * 32 + quad * 8];
            const short8 bl = *(const short8*)&BL[(n * 16 + lr) * 72 + k * 32 + quad * 8];
            y[n] = __builtin_amdgcn_mfma_f32_16x16x32_bf16(aH, bh, y[n], 0, 0, 0);
            y[n] = __builtin_amdgcn_mfma_f32_16x16x32_bf16(aH, bl, y[n], 0, 0, 0);
            y[n] = __builtin_amdgcn_mfma_f32_16x16x32_bf16(aL, bh, y[n], 0, 0, 0);
        }
    }
    const int orow = bg * 64 + w * 16 + quad * 4;
    #pragma unroll
    for (int n = 0; n < 4; ++n)
        #pragma unroll
        for (int i = 0; i < 4; ++i)
            y1[(orow + i) * 64 + n * 16 + lr] = (unsigned short)bfr(y[n][i]);
}

// ---------------------------------------------------------------------------
// Kernel C (MFMA): out = (gather(y1, idx1) + y1 + h) @ Wu^T + bu
// y1/h arrive bf16 (8B loads); X summed in fp32 then SPLIT hi/lo bf16 so the
// MFMA sees X to 2^-17 -- this removes the old dominant 2^-6 rounding error.
// LDS 18.4 KB -> still 8 blocks/CU. 96 MFMA/wave (still trivial vs traffic).
// ---------------------------------------------------------------------------
__global__ __launch_bounds__(256) void kC(const unsigned short* __restrict__ h,
                                          const unsigned short* __restrict__ y1,
                                          const int*   __restrict__ idx1,
                                          const unsigned short* __restrict__ WuB,
                                          const float* __restrict__ bu,
                                          float* __restrict__ out) {
    __shared__ unsigned short XsH[64 * 72];   // [m][k] hi, stride 72
    __shared__ unsigned short XsL[64 * 72];   // [m][k] lo
    const int tid = threadIdx.x;
    const int bid = ((blockIdx.x & 7) << 8) | (blockIdx.x >> 3);  // XCD swizzle
    const int m0 = bid * 64;
    const int b  = m0 >> 13;
    const int n0 = m0 & (NN - 1);

    // stage X = gather(y1) + y1 + h (fp32 sum), split into hi/lo bf16
    #pragma unroll
    for (int it = 0; it < 4; ++it) {
        int idx = it * 256 + tid;
        int r = idx >> 4, kq = idx & 15;
        int i1 = idx1[b * NN + n0 + r];
        const ushortx4 ya = *(const ushortx4*)&y1[(b * NN + i1) * 64 + kq * 4];
        const ushortx4 yb = *(const ushortx4*)&y1[(m0 + r) * 64 + kq * 4];
        const ushortx4 hh = *(const ushortx4*)&h [(m0 + r) * 64 + kq * 4];
        #pragma unroll
        for (int j = 0; j < 4; ++j) {
            float xv = b2f(ya[j]) + b2f(yb[j]) + b2f(hh[j]);
            unsigned xh = bfr(xv);
            XsH[r * 72 + kq * 4 + j] = (unsigned short)xh;
            XsL[r * 72 + kq * 4 + j] =
                (unsigned short)bfr(xv - __uint_as_float(xh << 16));
        }
    }
    __syncthreads();

    const int lane = tid & 63, w = tid >> 6;
    const int quad = lane >> 4, lr = lane & 15;
    const short8 a0h = *(const short8*)&XsH[(w * 16 + lr) * 72 + quad * 8];
    const short8 a0l = *(const short8*)&XsL[(w * 16 + lr) * 72 + quad * 8];
    const short8 a1h = *(const short8*)&XsH[(w * 16 + lr) * 72 + 32 + quad * 8];
    const short8 a1l = *(const short8*)&XsL[(w * 16 + lr) * 72 + 32 + quad * 8];
    const int orow0 = m0 + w * 16 + quad * 4;

    #pragma unroll
    for (int nt = 0; nt < 24; ++nt) {
        const short8 b0 = *(const short8*)&WuB[(nt * 16 + lr) * 64 + quad * 8];
        const short8 b1 = *(const short8*)&WuB[(nt * 16 + lr) * 64 + 32 + quad * 8];
        floatx4 d = {};
        d = __builtin_amdgcn_mfma_f32_16x16x32_bf16(a0h, b0, d, 0, 0, 0);
        d = __builtin_amdgcn_mfma_f32_16x16x32_bf16(a0l, b0, d, 0, 0, 0);
        d = __builtin_amdgcn_mfma_f32_16x16x32_bf16(a1h, b1, d, 0, 0, 0);
        d = __builtin_amdgcn_mfma_f32_16x16x32_bf16(a1l, b1, d, 0, 0, 0);
        const float bb = bu[nt * 16 + lr];
        #pragma unroll
        for (int i = 0; i < 4; ++i)
            out[(orow0 + i) * DD + nt * 16 + lr] = d[i] + bb;
    }
}

// ---------------------------------------------------------------------------
extern "C" void kernel_launch(void* const* d_in, const int* in_sizes, int n_in,
                              void* d_out, int out_size, void* d_ws, size_t ws_size,
                              hipStream_t stream) {
    const float* input = (const float*)d_in[0];
    const float* subU  = (const float*)d_in[1];
    const int*   idx   = (const int*)  d_in[2];
    const float* Wd    = (const float*)d_in[3];
    const float* bd    = (const float*)d_in[4];
    const float* Wu    = (const float*)d_in[5];
    const float* bu    = (const float*)d_in[6];
    const float* Wa    = (const float*)d_in[7];
    const float* ba    = (const float*)d_in[8];
    const float* gamma = (const float*)d_in[9];
    const float* beta  = (const float*)d_in[10];
    float* out = (float*)d_out;

    unsigned short* h16  = (unsigned short*)d_ws;          // [BN,64] bf16
    unsigned short* y116 = h16 + 8388608;                  // [BN,64] bf16
    unsigned short* WdB  = y116 + 8388608;                 // 64*384 bf16
    unsigned short* WuB  = WdB + 24576;                    // 384*64 bf16
    unsigned short* WaB  = WuB + 24576;                    // 64*64  bf16

    const float* U1   = subU + 8388608; // sub_U[1] (branch 0 is dead code)
    const int*   idx0 = idx;
    const int*   idx1 = idx + BNROW;

    kP<<<52,   256, 0, stream>>>(Wd, Wu, Wa, WdB, WuB, WaB);
    kA<<<2048, 256, 0, stream>>>(input, WdB, bd, h16);
    kB<<<2048, 256, 0, stream>>>(h16, U1, idx0, WaB, ba, gamma, beta, y116);
    kC<<<2048, 256, 0, stream>>>(h16, y116, idx1, WuB, bu, out);
}